// Round 1
// 748.980 us; speedup vs baseline: 1.0277x; 1.0277x over previous
//
#include <hip/hip_runtime.h>

#define DIM 4096
#define SEQ 2048
#define NH 32
#define HD 128

typedef __bf16 bf16x8 __attribute__((ext_vector_type(8)));
typedef float f32x4 __attribute__((ext_vector_type(4)));

// log2(e) / sqrt(HD): folded into Q so softmax runs in exp2 domain
#define QSCALE 0.12751649736765598f

__device__ inline ushort f2bf(float f) {
    union { float f; unsigned u; } v; v.f = f;
    unsigned r = v.u + 0x7fffu + ((v.u >> 16) & 1u);
    return (ushort)(r >> 16);
}

// ---------------- fused fp32 -> bf16 convert for x + all 4 weights ----------------
__global__ void conv_all(const float* __restrict__ x,  const float* __restrict__ wq,
                         const float* __restrict__ wk, const float* __restrict__ wv,
                         const float* __restrict__ wo,
                         ushort* __restrict__ xb,  ushort* __restrict__ wqb,
                         ushort* __restrict__ wkb, ushort* __restrict__ wvb,
                         ushort* __restrict__ wob) {
    int i = blockIdx.x * 256 + threadIdx.x;   // over (SEQ*DIM + 4*DIM*DIM)/4 float4s
    const float* src; ushort* dst; int off;
    const int n4x = (SEQ * DIM) / 4;          // 2^21
    if (i < n4x) { src = x; dst = xb; off = i; }
    else {
        int j = i - n4x;
        int w = j >> 22;                      // DIM*DIM/4 = 2^22
        off = j & ((1 << 22) - 1);
        src = (w == 0) ? wq : (w == 1) ? wk : (w == 2) ? wv : wo;
        dst = (w == 0) ? wqb : (w == 1) ? wkb : (w == 2) ? wvb : wob;
    }
    float4 v = ((const float4*)src)[off];
    ushort4 o;
    o.x = f2bf(v.x); o.y = f2bf(v.y); o.z = f2bf(v.z); o.w = f2bf(v.w);
    ((ushort4*)dst)[off] = o;
}

// ============================================================================
// 256x256 8-phase GEMM body (HK-style schedule in plain HIP).
//   BM=BN=256, BK=64, 512 threads = 8 waves (2M x 4N), per-wave C = 128x64.
//   LDS: 2 x (256x64) per operand, double-buffered = 128 KiB.
//   Per K-tile: 4 phases, each = {ds_read quadrant frags | issue 1 half-tile
//   prefetch | barrier | lgkmcnt(0) | setprio(1) 16xMFMA setprio(0) | barrier}.
//   Halves: A0 = rows {0-63,128-191} (quadrant mh=0 for both wm), A1 = rest;
//           B0 = 32-row blocks {0,2,4,6} (nh=0 for all wn), B1 = rest.
//   Prefetch schedule (tile T+1's halves issued at T-1.p3, T-1.p4, T.p1, T.p2;
//   tile T+2's A0,B0 at T.p3, T.p4) => boundary s_waitcnt vmcnt(4) guarantees
//   everything tile T+1 reads while 2 half-tiles stay in flight. Never vmcnt(0)
//   in steady state. Swizzle: row r stores global 16B-chunk g at pos g^(r&7);
//   all frag rows == c (mod 16) so readers use pos (gc^(c&7)) -- conflict-free
//   (verified SQ_LDS_BANK_CONFLICT==0 on the 128^2 ancestor).
// ============================================================================

#define AS1(p) (const __attribute__((address_space(1))) void*)(p)
#define AS3(p) (__attribute__((address_space(3))) void*)(p)
#define FENCE() asm volatile("" ::: "memory")
#define BARRIER() do { FENCE(); __builtin_amdgcn_sched_barrier(0); \
    __builtin_amdgcn_s_barrier(); \
    __builtin_amdgcn_sched_barrier(0); FENCE(); } while (0)
#define LGKM0() do { asm volatile("s_waitcnt lgkmcnt(0)" ::: "memory"); \
    __builtin_amdgcn_sched_barrier(0); } while (0)

__device__ __forceinline__ void gemm256_body(
    const ushort* __restrict__ Ab,   // pre-offset to tile row 0 (row-major, stride K)
    const ushort* __restrict__ Bb,   // pre-offset to tile col 0 (row-major, stride K)
    ushort* __restrict__ sA0, ushort* __restrict__ sA1,
    ushort* __restrict__ sB0, ushort* __restrict__ sB1,
    f32x4 acc[8][4], const int K)
{
    const int tid  = threadIdx.x;
    const int wave = tid >> 6, lane = tid & 63;
    const int quad = lane >> 4, c = lane & 15;
    const int wm = wave >> 2, wn = wave & 3;

    // staging: per global_load_lds a wave covers 8 rows x 64 cols (lane>>3 = row,
    // lane&7 = LDS chunk pos; fetch global chunk (lane&7)^(lane>>3))
    const int aoff = (lane >> 3) * K + (((lane & 7) ^ (lane >> 3)) * 8);
    const int sa_r0 = wave * 8;                                   // + h*64 (+128)
    const int sb_r0 = (wave >> 1) * 64 + (wave & 1) * 16;         // + h*32 (+8)

    // fragment read chunk positions for the two K-sub-steps
    const int rp0 = ((0 * 4 + quad) ^ (c & 7)) * 8;
    const int rp1 = ((1 * 4 + quad) ^ (c & 7)) * 8;
    const int arow = (wm * 128 + c) * 64;   // + mh*64*64 + mt*16*64
    const int brow = (wn * 64 + c) * 64;    // + nh*32*64 + nt*16*64

#define STAGE_A(dst, h, k0) do { \
    const int _r0 = (h) * 64 + sa_r0; \
    __builtin_amdgcn_global_load_lds(AS1(Ab + (size_t)_r0 * K + (k0) + aoff), \
                                     AS3((dst) + _r0 * 64), 16, 0, 0); \
    const int _r1 = _r0 + 128; \
    __builtin_amdgcn_global_load_lds(AS1(Ab + (size_t)_r1 * K + (k0) + aoff), \
                                     AS3((dst) + _r1 * 64), 16, 0, 0); \
  } while (0)
#define STAGE_B(dst, h, k0) do { \
    const int _r0 = (h) * 32 + sb_r0; \
    __builtin_amdgcn_global_load_lds(AS1(Bb + (size_t)_r0 * K + (k0) + aoff), \
                                     AS3((dst) + _r0 * 64), 16, 0, 0); \
    const int _r1 = _r0 + 8; \
    __builtin_amdgcn_global_load_lds(AS1(Bb + (size_t)_r1 * K + (k0) + aoff), \
                                     AS3((dst) + _r1 * 64), 16, 0, 0); \
  } while (0)

    bf16x8 af[4][2], bfr[2][2];

#define READ_AH(buf, mh) do { \
    _Pragma("unroll") \
    for (int mt = 0; mt < 4; ++mt) { \
        af[mt][0] = *(const bf16x8*)&(buf)[arow + (mh) * 4096 + mt * 1024 + rp0]; \
        af[mt][1] = *(const bf16x8*)&(buf)[arow + (mh) * 4096 + mt * 1024 + rp1]; \
    } } while (0)
#define READ_BH(buf, nh) do { \
    _Pragma("unroll") \
    for (int nt = 0; nt < 2; ++nt) { \
        bfr[nt][0] = *(const bf16x8*)&(buf)[brow + (nh) * 2048 + nt * 1024 + rp0]; \
        bfr[nt][1] = *(const bf16x8*)&(buf)[brow + (nh) * 2048 + nt * 1024 + rp1]; \
    } } while (0)
#define MMA_Q(mh, nh) do { \
    __builtin_amdgcn_s_setprio(1); \
    _Pragma("unroll") \
    for (int kk = 0; kk < 2; ++kk) \
    _Pragma("unroll") \
    for (int mt = 0; mt < 4; ++mt) \
    _Pragma("unroll") \
    for (int nt = 0; nt < 2; ++nt) \
        acc[(mh)*4+mt][(nh)*2+nt] = __builtin_amdgcn_mfma_f32_16x16x32_bf16( \
            af[mt][kk], bfr[nt][kk], acc[(mh)*4+mt][(nh)*2+nt], 0, 0, 0); \
    __builtin_amdgcn_s_setprio(0); \
  } while (0)

    const int NT = K >> 6;

    // prologue: tile0 complete + A0,B0 of tile1 (12 loads); wait all but last 4
    STAGE_A(sA0, 0, 0);  STAGE_B(sB0, 0, 0);
    STAGE_A(sA0, 1, 0);  STAGE_B(sB0, 1, 0);
    STAGE_A(sA1, 0, 64); STAGE_B(sB1, 0, 64);
    asm volatile("s_waitcnt vmcnt(4)" ::: "memory");
    BARRIER();

    for (int t = 0; t < NT; ++t) {
        ushort* cA = (t & 1) ? sA1 : sA0;
        ushort* cB = (t & 1) ? sB1 : sB0;
        ushort* nA = (t & 1) ? sA0 : sA1;
        ushort* nB = (t & 1) ? sB0 : sB1;
        const int kn  = (t + 1) << 6;
        const int kn2 = (t + 2) << 6;
        const bool ok1 = (t + 1 < NT), ok2 = (t + 2 < NT);

        // phase 1: quadrant (A0,B0); issue A1 of tile t+1
        READ_AH(cA, 0); READ_BH(cB, 0);
        if (ok1) STAGE_A(nA, 1, kn);
        BARRIER(); LGKM0();
        MMA_Q(0, 0);
        BARRIER();

        // phase 2: quadrant (A0,B1); issue B1 of tile t+1
        READ_BH(cB, 1);
        if (ok1) STAGE_B(nB, 1, kn);
        BARRIER(); LGKM0();
        MMA_Q(0, 1);
        BARRIER();

        // phase 3: quadrant (A1,B0); issue A0 of tile t+2 (A0 last read in p2)
        READ_AH(cA, 1); READ_BH(cB, 0);
        if (ok2) STAGE_A(cA, 0, kn2);
        BARRIER(); LGKM0();
        MMA_Q(1, 0);
        BARRIER();

        // phase 4: quadrant (A1,B1); issue B0 of tile t+2 (B0 last read in p3)
        READ_BH(cB, 1);
        if (ok2) STAGE_B(cB, 0, kn2);
        BARRIER(); LGKM0();
        MMA_Q(1, 1);
        if (t < NT - 1) {
            if (ok2) asm volatile("s_waitcnt vmcnt(4)" ::: "memory");
            else     asm volatile("s_waitcnt vmcnt(0)" ::: "memory");
        }
        BARRIER();
    }
#undef STAGE_A
#undef STAGE_B
#undef READ_AH
#undef READ_BH
#undef MMA_Q
}

// ---------------- fused QKV GEMM, 256^2 tiles, rotary folded into epilogue ----------------
// Grid 384 (8 m-tiles x 48 n-tiles), XCD n-partition: XCD x=bi&7 owns 6 n-tiles,
// m sweeps fastest (A stays L3-hot; per-XCD B window in its L2).
__global__ __launch_bounds__(512, 2)
void gemm_qkv(const ushort* __restrict__ A,
              const ushort* __restrict__ Bq, const ushort* __restrict__ Bk,
              const ushort* __restrict__ Bv,
              ushort* __restrict__ qout, ushort* __restrict__ kout,
              ushort* __restrict__ vt, const float* __restrict__ freqs) {
    __shared__ __align__(16) ushort sA[2][256 * 64];
    __shared__ __align__(16) ushort sB[2][256 * 64];
    const int bi = blockIdx.x;
    const int x = bi & 7;                    // XCD (round-robin dispatch)
    const int l = bi >> 3;                   // 0..47 within XCD
    const int mblk = l & 7;
    const int nblk = x * 6 + (l >> 3);       // 0..47, exclusive per XCD
    const int wsel = nblk >> 4;              // 0=q 1=k 2=v
    const int nloc = (nblk & 15) * 256;
    const int m0 = mblk * 256;
    const ushort* B = (wsel == 0) ? Bq : (wsel == 1) ? Bk : Bv;

    const f32x4 vzero = {0.f, 0.f, 0.f, 0.f};
    f32x4 acc[8][4];
#pragma unroll
    for (int i = 0; i < 8; i++)
#pragma unroll
        for (int j = 0; j < 4; j++) acc[i][j] = vzero;

    gemm256_body(A + (size_t)m0 * DIM, B + (size_t)nloc * DIM,
                 &sA[0][0], &sA[1][0], &sB[0][0], &sB[1][0], acc, DIM);

    const int tid = threadIdx.x;
    const int wave = tid >> 6, lane = tid & 63;
    const int quad = lane >> 4, c = lane & 15;
    const int wm = wave >> 2, wn = wave & 3;

    if (wsel < 2) {
        ushort* Cw = wsel ? kout : qout;
        const float qs = wsel ? 1.0f : QSCALE;
#pragma unroll
        for (int i = 0; i < 8; i++) {
#pragma unroll
            for (int j = 0; j < 4; j++) {
                int colg = nloc + wn * 64 + j * 16 + c;
                int dh = (colg & 127) >> 1;
#pragma unroll
                for (int r = 0; r < 4; r++) {
                    int row = m0 + wm * 128 + i * 16 + quad * 4 + r;
                    float2 f2 = ((const float2*)freqs)[row * 64 + dh];
                    float f = (f2.x + ((c & 1) ? f2.y : -f2.y)) * qs;
                    Cw[(size_t)row * DIM + colg] = f2bf(acc[i][j][r] * f);
                }
            }
        }
    } else {
        // V: write transposed vt[cv][seq]; lane holds 4 consecutive seq rows
#pragma unroll
        for (int i = 0; i < 8; i++) {
#pragma unroll
            for (int j = 0; j < 4; j++) {
                int cv = nloc + wn * 64 + j * 16 + c;
                int row0 = m0 + wm * 128 + i * 16 + quad * 4;
                ushort4 o;
                o.x = f2bf(acc[i][j][0]); o.y = f2bf(acc[i][j][1]);
                o.z = f2bf(acc[i][j][2]); o.w = f2bf(acc[i][j][3]);
                *(ushort4*)&vt[(size_t)cv * SEQ + row0] = o;
            }
        }
    }
}

// ---------------- bf16 GEMM, 256^2 tiles, fp32 output (final projection) ----------------
// Grid 128 (8 m-tiles x 16 n-tiles), XCD owns 2 n-tiles, m fastest.
__global__ __launch_bounds__(512, 2)
void gemm_f32out(const ushort* __restrict__ A, const ushort* __restrict__ B,
                 float* __restrict__ C, int M, int N, int K) {
    __shared__ __align__(16) ushort sA[2][256 * 64];
    __shared__ __align__(16) ushort sB[2][256 * 64];
    const int bi = blockIdx.x;
    const int x = bi & 7;
    const int l = bi >> 3;                   // 0..15
    const int mblk = l & 7;
    const int nblk = x * 2 + (l >> 3);       // 0..15
    const int m0 = mblk * 256, n0 = nblk * 256;

    const f32x4 vzero = {0.f, 0.f, 0.f, 0.f};
    f32x4 acc[8][4];
#pragma unroll
    for (int i = 0; i < 8; i++)
#pragma unroll
        for (int j = 0; j < 4; j++) acc[i][j] = vzero;

    gemm256_body(A + (size_t)m0 * K, B + (size_t)n0 * K,
                 &sA[0][0], &sA[1][0], &sB[0][0], &sB[1][0], acc, K);

    const int tid = threadIdx.x;
    const int wave = tid >> 6, lane = tid & 63;
    const int quad = lane >> 4, c = lane & 15;
    const int wm = wave >> 2, wn = wave & 3;

#pragma unroll
    for (int i = 0; i < 8; i++)
#pragma unroll
        for (int j = 0; j < 4; j++)
#pragma unroll
            for (int r = 0; r < 4; r++) {
                int row = m0 + wm * 128 + i * 16 + quad * 4 + r;
                int col = n0 + wn * 64 + j * 16 + c;
                C[(size_t)row * N + col] = acc[i][j][r];
            }
}

// ---------------- flash attention (causal), balanced pairing + swizzled LDS ----------------
// 512 blocks: block handles head h = bi&31 and q-block pair {p, 31-p}, p = bi>>5
// -> exactly 33 K-tile iterations per block (perfect balance).
__global__ __launch_bounds__(256)
void flash_kernel(const ushort* __restrict__ Q, const ushort* __restrict__ K,
                  const ushort* __restrict__ Vt, ushort* __restrict__ O) {
    const int bi = blockIdx.x;
    const int h = bi & (NH - 1);
    const int p = bi >> 5;
    __shared__ __align__(16) ushort sK[64 * 128];
    __shared__ __align__(16) ushort sVt[128 * 64];
    __shared__ __align__(16) ushort sP[4][16 * 72];
    const int tid = threadIdx.x, wave = tid >> 6, lane = tid & 63;
    const int quad = lane >> 4, c = lane & 15;

    for (int pass = 0; pass < 2; pass++) {
        const int qb = pass ? (SEQ / 64 - 1 - p) : p;
        const int q0 = qb * 64;

        bf16x8 qf[4];
        {
            const ushort* Qp = Q + (size_t)(q0 + wave * 16 + c) * DIM + h * HD;
#pragma unroll
            for (int ks = 0; ks < 4; ks++) qf[ks] = *(const bf16x8*)(Qp + ks * 32 + quad * 8);
        }
        const f32x4 vzero = {0.f, 0.f, 0.f, 0.f};
        f32x4 oa[8];
#pragma unroll
        for (int dt = 0; dt < 8; dt++) oa[dt] = vzero;
        float ms[4], ls[4];
#pragma unroll
        for (int r = 0; r < 4; r++) { ms[r] = -1e30f; ls[r] = 0.f; }

        for (int kt = 0; kt <= qb; kt++) {
            __syncthreads();
            // stage K tile [64 keys][128 d]: wave covers 16 rows in 4 insts
#pragma unroll
            for (int i = 0; i < 4; i++) {
                int lr = wave * 16 + i * 4 + (lane >> 4);
                int ch = lane & 15;
                int g = (ch & 8) | ((ch ^ lr) & 7);
                __builtin_amdgcn_global_load_lds(
                    (const __attribute__((address_space(1))) void*)(K + (size_t)(kt * 64 + lr) * DIM + h * HD + g * 8),
                    (__attribute__((address_space(3))) void*)(&sK[(wave * 16 + i * 4) * 128]), 16, 0, 0);
            }
            // stage V^T tile [128 d][64 keys]: wave covers 32 rows in 4 insts
#pragma unroll
            for (int i = 0; i < 4; i++) {
                int ld = wave * 32 + i * 8 + (lane >> 3);
                int ch = lane & 7;
                int g = (ch ^ ld) & 7;
                __builtin_amdgcn_global_load_lds(
                    (const __attribute__((address_space(1))) void*)(Vt + (size_t)(h * HD + ld) * SEQ + kt * 64 + g * 8),
                    (__attribute__((address_space(3))) void*)(&sVt[(wave * 32 + i * 8) * 64]), 16, 0, 0);
            }
            __syncthreads();

            // S = Q K^T (Q pre-scaled by log2e/sqrt(HD))
            f32x4 s[4];
#pragma unroll
            for (int nt = 0; nt < 4; nt++) s[nt] = vzero;
#pragma unroll
            for (int ks = 0; ks < 4; ks++)
#pragma unroll
                for (int nt = 0; nt < 4; nt++) {
                    int lr = nt * 16 + c;
                    int gc = ks * 4 + quad;
                    int pch = (gc & 8) | ((gc ^ lr) & 7);
                    bf16x8 kf = *(const bf16x8*)&sK[lr * 128 + pch * 8];
                    s[nt] = __builtin_amdgcn_mfma_f32_16x16x32_bf16(qf[ks], kf, s[nt], 0, 0, 0);
                }

            if (kt == qb) {  // causal mask on the diagonal tile
#pragma unroll
                for (int nt = 0; nt < 4; nt++)
#pragma unroll
                    for (int r = 0; r < 4; r++) {
                        int keyg = nt * 16 + c;
                        int qg   = wave * 16 + quad * 4 + r;
                        if (keyg > qg) s[nt][r] = -1e30f;
                    }
            }

            // online softmax (exp2 domain)
            float mnew[4], alpha[4];
#pragma unroll
            for (int r = 0; r < 4; r++) {
                float v = fmaxf(fmaxf(s[0][r], s[1][r]), fmaxf(s[2][r], s[3][r]));
                v = fmaxf(v, __shfl_xor(v, 1));
                v = fmaxf(v, __shfl_xor(v, 2));
                v = fmaxf(v, __shfl_xor(v, 4));
                v = fmaxf(v, __shfl_xor(v, 8));
                mnew[r]  = fmaxf(ms[r], v);
                alpha[r] = exp2f(ms[r] - mnew[r]);
                ms[r]    = mnew[r];
            }
            float rs[4] = {0.f, 0.f, 0.f, 0.f};
#pragma unroll
            for (int nt = 0; nt < 4; nt++)
#pragma unroll
                for (int r = 0; r < 4; r++) {
                    float pv = exp2f(s[nt][r] - mnew[r]);
                    rs[r] += pv;
                    sP[wave][(quad * 4 + r) * 72 + nt * 16 + c] = f2bf(pv);
                }
#pragma unroll
            for (int r = 0; r < 4; r++) {
                float v = rs[r];
                v += __shfl_xor(v, 1);
                v += __shfl_xor(v, 2);
                v += __shfl_xor(v, 4);
                v += __shfl_xor(v, 8);
                ls[r] = ls[r] * alpha[r] + v;
            }
#pragma unroll
            for (int dt = 0; dt < 8; dt++)
#pragma unroll
                for (int r = 0; r < 4; r++) oa[dt][r] *= alpha[r];

            __asm__ volatile("s_waitcnt lgkmcnt(0)" ::: "memory");  // drain wave-private sP writes

            // O += P V
#pragma unroll
            for (int k2 = 0; k2 < 2; k2++) {
                bf16x8 pf = *(const bf16x8*)&sP[wave][c * 72 + k2 * 32 + quad * 8];
#pragma unroll
                for (int dt = 0; dt < 8; dt++) {
                    int ld = dt * 16 + c;
                    int gc = k2 * 4 + quad;
                    int pch = (gc ^ ld) & 7;
                    bf16x8 vf = *(const bf16x8*)&sVt[ld * 64 + pch * 8];
                    oa[dt] = __builtin_amdgcn_mfma_f32_16x16x32_bf16(pf, vf, oa[dt], 0, 0, 0);
                }
            }
        }

        // epilogue
#pragma unroll
        for (int r = 0; r < 4; r++) {
            float inv = 1.f / ls[r];
            int row = q0 + wave * 16 + quad * 4 + r;
#pragma unroll
            for (int dt = 0; dt < 8; dt++)
                O[(size_t)row * DIM + h * HD + dt * 16 + c] = f2bf(oa[dt][r] * inv);
        }
    }
}

extern "C" void kernel_launch(void* const* d_in, const int* in_sizes, int n_in,
                              void* d_out, int out_size, void* d_ws, size_t ws_size,
                              hipStream_t stream) {
    const float* x     = (const float*)d_in[0];
    const float* freqs = (const float*)d_in[2];
    const float* wq    = (const float*)d_in[4];
    const float* wk    = (const float*)d_in[5];
    const float* wv    = (const float*)d_in[6];
    const float* wo    = (const float*)d_in[7];
    float* out = (float*)d_out;

    ushort* xb    = (ushort*)d_ws;
    ushort* wqb   = xb    + (size_t)SEQ * DIM;
    ushort* wkb   = wqb   + (size_t)DIM * DIM;
    ushort* wvb   = wkb   + (size_t)DIM * DIM;
    ushort* wob   = wvb   + (size_t)DIM * DIM;
    ushort* qbuf  = wob   + (size_t)DIM * DIM;
    ushort* kbuf  = qbuf  + (size_t)SEQ * DIM;
    ushort* vtbuf = kbuf  + (size_t)SEQ * DIM;   // [DIM][SEQ] = V^T per head
    ushort* obuf  = vtbuf + (size_t)SEQ * DIM;

    const int n4tot = (SEQ * DIM + 4 * DIM * DIM) / 4;
    conv_all<<<n4tot / 256, 256, 0, stream>>>(x, wq, wk, wv, wo, xb, wqb, wkb, wvb, wob);

    // 8 m-tiles x (3*16) n-tiles of 256^2
    gemm_qkv<<<dim3(384), 512, 0, stream>>>(xb, wqb, wkb, wvb, qbuf, kbuf, vtbuf, freqs);

    flash_kernel<<<dim3(NH * SEQ / 128), 256, 0, stream>>>(qbuf, kbuf, vtbuf, obuf);

    // 8 m-tiles x 16 n-tiles of 256^2
    gemm_f32out<<<dim3(128), 512, 0, stream>>>(obuf, wob, out, SEQ, DIM, DIM);
}